// Round 8
// baseline (351.190 us; speedup 1.0000x reference)
//
#include <hip/hip_runtime.h>

// NLSearch: B=1, T=4, C=64 (2 heads x 32ch), H=W=192, stride0=4 -> 48x48 queries,
// patch 7x7, offsets dt{-1,0,1} x di,dj{-3..4} (L=192), top-K=7.
// Out: vals f32 [2][9216][7] (129024) then inds [2][9216][7][3] (387072).
//
// R8 structure: transpose vid1 -> [t][h][w][c] in d_ws (coalesced lane=c reads);
// main kernel stages only the small A patch (vid0, original layout) to LDS,
// reads B straight from the transposed global copy (L2/L3-resident), and runs
// the 3-dt loop with ZERO inter-dt barriers: dup-dt (clamp(t+dt) collision)
// slots are written from the SAME acc registers -> bitwise-equal scores, so
// jax top_k's lower-index tie-break is reproduced exactly.
//
// Hard-won lessons kept:
//  - NO min-waves arg in __launch_bounds__: (256,3)->84 and (256,4)->64 VGPR
//    caps spilled a[]/acc[] to scratch (R3: 3.1 GB scratch HBM traffic).
//  - LDS c-strides ODD (A: 79) -> no bank conflicts (R7 measured 0).
//  - Fatter blocks beat thin ones (R6: 2x blocks, half compute each = +86%).
//  - Fallback to the proven R5 LDS kernel if ws_size < 37.75 MB.

#define HH 192
#define WW 192
#define HW (HH * WW)
#define TSLICE (192 * 192 * 64)   // one t-slice of transposed vid1 (floats)
#define ROWST  (192 * 64)         // h-row stride in transposed layout (floats)
#define TVID   (4 * TSLICE)

#define AS_CSTR 79                // 7*11 + 2 pad, ODD -> conflict-free b32

__device__ __forceinline__ int reflect_i(int idx, int n) {
    idx = idx < 0 ? -idx : idx;
    idx = idx >= n ? 2 * (n - 1) - idx : idx;
    return idx;
}

template <int CTRL>
__device__ __forceinline__ float dpp_add(float x) {
    int y = __builtin_amdgcn_update_dpp(0, __float_as_int(x), CTRL, 0xf, 0xf, true);
    return x + __int_as_float(y);
}

// lane31 <- sum(lanes 0..31), lane63 <- sum(lanes 32..63); VALU pipe, no LDS.
__device__ __forceinline__ float reduce32(float v) {
    v = dpp_add<0x111>(v);  // row_shr:1
    v = dpp_add<0x112>(v);  // row_shr:2
    v = dpp_add<0x114>(v);  // row_shr:4
    v = dpp_add<0x118>(v);  // row_shr:8
    v = dpp_add<0x142>(v);  // row_bcast15
    return v;
}

// ---------------- transpose vid1 [t][c][h][w] -> [t][h][w][c] ----------------
__global__ __launch_bounds__(256) void transpose_k(
    const float* __restrict__ v1, float* __restrict__ ws)
{
    __shared__ float tile[64 * 65];
    const int wt  = blockIdx.x;      // 0..2  (w tile of 64)
    const int h   = blockIdx.y;      // 0..191
    const int t   = blockIdx.z;      // 0..3
    const int w0  = wt * 64;
    const int tid = threadIdx.x;
    const int a   = tid & 63;
    const int g   = tid >> 6;
    const float* src = v1 + (size_t)t * 64 * HW + h * WW + w0;
    float* dst = ws + ((size_t)(t * 192 + h) * 192 + w0) * 64;
    #pragma unroll
    for (int cc = g; cc < 64; cc += 4)
        tile[cc * 65 + a] = src[(size_t)cc * HW + a];
    __syncthreads();
    #pragma unroll
    for (int ww = g; ww < 64; ww += 4)
        dst[ww * 64 + a] = tile[a * 65 + ww];
}

// ---------------- main kernel: barrier-free dt loop --------------------------
__global__ __launch_bounds__(256) void nls_fast(
    const float* __restrict__ vid0,
    const float* __restrict__ T1,
    float* __restrict__ out)
{
    __shared__ float As[32 * AS_CSTR];   // A union patch for the query pair
    __shared__ float score[2 * 192];

    // XCD swizzle: xcd = blk&7 -> qi band of 6; inner (hd, t, qi_l, qjp fastest)
    const int b    = blockIdx.x;
    const int xcd  = b & 7;
    const int loc  = b >> 3;
    const int qjp  = loc % 24;
    const int r1   = loc / 24;
    const int qi_l = r1 % 6;
    const int r2   = r1 / 6;
    const int t    = r2 & 3;
    const int hd   = r2 >> 2;
    const int qi   = xcd * 6 + qi_l;

    const int qh  = qi * 4;
    const int qw0 = qjp * 8;

    const int tid  = threadIdx.x;
    const int lane = tid & 63;
    const int wid  = tid >> 6;

    // ---- stage A union [32c][7y][11x] from vid0 (original layout) ----
    {
        const int sc = tid >> 3;     // channel 0..31
        const int vl = tid & 7;      // row 0..7 (7 used)
        if (vl < 7) {
            const float* src = vid0 + (size_t)(t * 64 + hd * 32 + sc) * HW;
            const int hh = reflect_i(qh - 3 + vl, HH);
            const float* rp = src + hh * WW;
            float* dst = As + sc * AS_CSTR + vl * 11;
            #pragma unroll
            for (int x = 0; x < 11; ++x)
                dst[x] = rp[reflect_i(qw0 - 3 + x, WW)];
        }
    }
    __syncthreads();

    const int c     = lane & 31;
    const int hhalf = lane >> 5;   // dj half: 0 -> dj 0..3, 1 -> dj 4..7
    const int q     = wid >> 1;    // query in pair
    const int d     = wid & 1;     // di half: rows 4d..4d+3
    const int cg    = hd * 32 + c;
    const int qwq   = qw0 + 4 * q;

    // ---- A patch -> regs (from LDS, odd stride, conflict-free) ----
    float a[7][7];
    {
        const float* Ab = As + c * AS_CSTR + 4 * q;
        #pragma unroll
        for (int y = 0; y < 7; ++y)
            #pragma unroll
            for (int x = 0; x < 7; ++x)
                a[y][x] = Ab[y * 11 + x];
    }

    const bool interior = (qi >= 2) && (qi <= 46) && (qjp >= 1) && (qjp <= 22);

#define FMA_BLOCK                                                        \
    {                                                                    \
        const int dlo = r > 6 ? r - 6 : 0;                               \
        const int dhi = r < 3 ? r : 3;                                   \
        _Pragma("unroll")                                                \
        for (int dip = 0; dip < 4; ++dip) {                              \
            if (dip >= dlo && dip <= dhi) {                              \
                const int y = r - dip;                                   \
                _Pragma("unroll")                                        \
                for (int djp = 0; djp < 4; ++djp) {                      \
                    _Pragma("unroll")                                    \
                    for (int x = 0; x < 7; ++x) {                        \
                        acc[dip * 4 + djp] =                             \
                            fmaf(a[y][x], rw[djp + x], acc[dip * 4 + djp]); \
                    }                                                    \
                }                                                        \
            }                                                            \
        }                                                                \
    }

    // ---- 3-dt loop, NO barriers: dup dt re-writes the same registers ----
    float acc[16];
    int tprev = -1;
    #pragma unroll
    for (int dtI = 0; dtI < 3; ++dtI) {
        int tp = t + dtI - 1;
        tp = tp < 0 ? 0 : (tp > 3 ? 3 : tp);

        if (tp != tprev) {
            tprev = tp;
            #pragma unroll
            for (int k = 0; k < 16; ++k) acc[k] = 0.f;

            if (interior) {
                const float* P = T1 + (size_t)(tp * 192 + qh - 6 + 4 * d) * ROWST
                               + (qwq - 6 + 4 * hhalf) * 64 + cg;
                #pragma unroll
                for (int r = 0; r < 10; ++r) {
                    const float* pr = P + r * ROWST;
                    float rw[10];
                    #pragma unroll
                    for (int v = 0; v < 10; ++v) rw[v] = pr[v * 64];
                    FMA_BLOCK
                }
            } else {
                int wo[10];
                #pragma unroll
                for (int v = 0; v < 10; ++v)
                    wo[v] = reflect_i(qwq - 6 + 4 * hhalf + v, WW) * 64 + cg;
                const float* Pt = T1 + (size_t)tp * TSLICE;
                #pragma unroll
                for (int r = 0; r < 10; ++r) {
                    const int hv = reflect_i(qh - 6 + 4 * d + r, HH);
                    const float* pr = Pt + (size_t)hv * ROWST;
                    float rw[10];
                    #pragma unroll
                    for (int v = 0; v < 10; ++v) rw[v] = pr[wo[v]];
                    FMA_BLOCK
                }
            }

            // channel reduction on VALU; lane31 -> hhalf0, lane63 -> hhalf1
            #pragma unroll
            for (int k = 0; k < 16; ++k) acc[k] = reduce32(acc[k]);
        }

        // write this dt's slot (dup dt writes identical bits -> exact ties)
        if ((lane & 31) == 31) {
            float* sp = &score[q * 192 + dtI * 64 + 4 * hhalf];
            #pragma unroll
            for (int dip = 0; dip < 4; ++dip)
                #pragma unroll
                for (int djp = 0; djp < 4; ++djp)
                    sp[(4 * d + dip) * 8 + djp] = acc[dip * 4 + djp];
        }
    }
#undef FMA_BLOCK

    __syncthreads();

    // ---- top-K=7 over 192 per query; waves 0,1 ----
    if (wid < 2) {
        const int qq = wid;
        const int qj = 2 * qjp + qq;
        float v0 = score[qq * 192 + lane];
        float v1 = score[qq * 192 + 64 + lane];
        float v2 = score[qq * 192 + 128 + lane];
        const int qglob = (t * 48 + qi) * 48 + qj;
        const int vbase = (hd * 9216 + qglob) * 7;
        const int ibase = 129024 + vbase * 3;
        for (int r = 0; r < 7; ++r) {
            float bv = v0; int bi = lane;
            if (v1 > bv) { bv = v1; bi = lane + 64; }
            if (v2 > bv) { bv = v2; bi = lane + 128; }
            #pragma unroll
            for (int m = 1; m <= 32; m <<= 1) {
                float ov = __shfl_xor(bv, m);
                int   oi = __shfl_xor(bi, m);
                if (ov > bv || (ov == bv && oi < bi)) { bv = ov; bi = oi; }
            }
            if (lane == 0) {
                out[vbase + r] = bv;
                int dtSel = bi >> 6;
                int rr    = bi & 63;
                int diSel = (rr >> 3) - 3;
                int djSel = (rr & 7) - 3;
                int ts = t + dtSel - 1;
                ts = ts < 0 ? 0 : (ts > 3 ? 3 : ts);
                int hs = reflect_i(qh + diSel, HH);
                int ws = reflect_i(qj * 4 + djSel, WW);
                float* op = out + ibase + 3 * r;
                op[0] = (float)ts;
                op[1] = (float)hs;
                op[2] = (float)ws;
            }
            if ((bi & 63) == lane) {
                int slot = bi >> 6;
                if (slot == 0)      v0 = -3.4e38f;
                else if (slot == 1) v1 = -3.4e38f;
                else                v2 = -3.4e38f;
            }
        }
    }
}

// ---------------- fallback (proven R5 kernel, 331 us) if ws too small --------
#define BS_CSTR 282
#define BS_SZ   (32 * BS_CSTR)
#define AF_CSTR 86

__global__ __launch_bounds__(256) void nls_kernel(
    const float* __restrict__ vid0,
    const float* __restrict__ vid1,
    float* __restrict__ out)
{
    __shared__ float smem[BS_SZ + 2 * 192];
    float* Bs = smem;
    float* Asf = smem;
    float* score = smem + BS_SZ;

    const int b    = blockIdx.x;
    const int xcd  = b & 7;
    const int loc  = b >> 3;
    const int qjp  = loc % 24;
    const int r1   = loc / 24;
    const int qi_l = r1 % 6;
    const int r2   = r1 / 6;
    const int t    = r2 & 3;
    const int hd   = r2 >> 2;
    const int qi   = xcd * 6 + qi_l;

    const int qh  = qi * 4;
    const int qw0 = qjp * 8;

    const int tid  = threadIdx.x;
    const int lane = tid & 63;
    const int wid  = tid >> 6;

    const bool intA = (qi >= 1) && (qjp >= 1) && (qjp <= 22);
    const bool intB = (qi >= 2) && (qi <= 46) && (qjp >= 1) && (qjp <= 22);

    if (intA) {
        const int sc = tid & 31;
        const int gg = tid >> 5;
        const float* src = vid0 + (size_t)(t * 64 + hd * 32 + sc) * HW
                         + (qh - 3) * WW + (qw0 - 3);
        float* dstc = Asf + sc * AF_CSTR;
        for (int it = gg; it < 21; it += 8) {
            int u = it / 3, grp = it - u * 3;
            float4 val = *(const float4*)(src + u * WW + 4 * grp);
            float* dp = dstc + u * 12 + 4 * grp;
            *(float2*)(dp)     = make_float2(val.x, val.y);
            *(float2*)(dp + 2) = make_float2(val.z, val.w);
        }
    } else {
        const int sc = tid >> 3;
        const int vl = tid & 7;
        const float* src = vid0 + (size_t)(t * 64 + hd * 32 + sc) * HW;
        const int wa0 = reflect_i(qw0 - 3 + vl, WW);
        const int wa1 = (vl < 4) ? reflect_i(qw0 + 5 + vl, WW) : 0;
        float* dst = Asf + sc * AF_CSTR + vl;
        #pragma unroll
        for (int u = 0; u < 7; ++u) {
            int hh = reflect_i(qh - 3 + u, HH);
            const float* rp = src + hh * WW;
            dst[u * 12] = rp[wa0];
            if (vl < 4) dst[u * 12 + 8] = rp[wa1];
        }
    }
    __syncthreads();

    const int c     = lane & 31;
    const int hhalf = lane >> 5;
    const int q     = wid >> 1;
    const int d     = wid & 1;

    float a[7][8];
    {
        const float* Ab = Asf + c * AF_CSTR + 4 * q;
        #pragma unroll
        for (int y = 0; y < 7; ++y) {
            #pragma unroll
            for (int j = 0; j < 4; ++j)
                *(float2*)&a[y][2 * j] = *(const float2*)(Ab + y * 12 + 2 * j);
        }
    }

    const float* Bc = Bs + c * BS_CSTR + (4 * d) * 20 + 4 * q + 4 * hhalf;

    int tprev = -1;
    for (int dtI = 0; dtI < 3; ++dtI) {
        int tp = t + dtI - 1;
        tp = tp < 0 ? 0 : (tp > 3 ? 3 : tp);
        __syncthreads();
        if (tp == tprev) {
            if (tid < 128) {
                int qq = tid >> 6, o = tid & 63;
                score[qq * 192 + dtI * 64 + o] = score[qq * 192 + (dtI - 1) * 64 + o];
            }
            continue;
        }
        tprev = tp;

        if (intB) {
            const int sc = tid & 31;
            const int gg = tid >> 5;
            const float* src = vid1 + (size_t)(tp * 64 + hd * 32 + sc) * HW
                             + (qh - 6) * WW + (qw0 - 6);
            float* dstc = Bs + sc * BS_CSTR;
            for (int it = gg; it < 70; it += 8) {
                int u = it / 5, grp = it - u * 5;
                float4 val = *(const float4*)(src + u * WW + 4 * grp);
                float* dp = dstc + u * 20 + 4 * grp;
                *(float2*)(dp)     = make_float2(val.x, val.y);
                *(float2*)(dp + 2) = make_float2(val.z, val.w);
            }
        } else {
            const int sc = tid >> 3;
            const int vl = tid & 7;
            const float* src = vid1 + (size_t)(tp * 64 + hd * 32 + sc) * HW;
            const int w0 = reflect_i(qw0 - 6 + vl, WW);
            const int w1 = reflect_i(qw0 + 2 + vl, WW);
            const int w2 = (vl < 4) ? reflect_i(qw0 + 10 + vl, WW) : 0;
            float* dst = Bs + sc * BS_CSTR + vl;
            #pragma unroll
            for (int u = 0; u < 14; ++u) {
                int hh2 = reflect_i(qh - 6 + u, HH);
                const float* rp = src + hh2 * WW;
                dst[u * 20]     = rp[w0];
                dst[u * 20 + 8] = rp[w1];
                if (vl < 4) dst[u * 20 + 16] = rp[w2];
            }
        }
        __syncthreads();

        {
            float acc[16];
            #pragma unroll
            for (int k = 0; k < 16; ++k) acc[k] = 0.f;
            #pragma unroll
            for (int r = 0; r < 10; ++r) {
                float rw[12];
                const float* Br = Bc + r * 20;
                #pragma unroll
                for (int j = 0; j < 6; ++j)
                    *(float2*)&rw[2 * j] = *(const float2*)(Br + 2 * j);
                const int dlo = r > 6 ? r - 6 : 0;
                const int dhi = r < 3 ? r : 3;
                #pragma unroll
                for (int dip = 0; dip < 4; ++dip) {
                    if (dip >= dlo && dip <= dhi) {
                        const int y = r - dip;
                        #pragma unroll
                        for (int djp = 0; djp < 4; ++djp)
                            #pragma unroll
                            for (int x = 0; x < 7; ++x)
                                acc[dip * 4 + djp] =
                                    fmaf(a[y][x], rw[djp + x], acc[dip * 4 + djp]);
                    }
                }
            }
            #pragma unroll
            for (int k = 0; k < 16; ++k) acc[k] = reduce32(acc[k]);
            if ((lane & 31) == 31) {
                float* sp = &score[q * 192 + dtI * 64 + 4 * hhalf];
                #pragma unroll
                for (int dip = 0; dip < 4; ++dip) {
                    float* dp = sp + (4 * d + dip) * 8;
                    *(float2*)(dp)     = make_float2(acc[dip * 4 + 0], acc[dip * 4 + 1]);
                    *(float2*)(dp + 2) = make_float2(acc[dip * 4 + 2], acc[dip * 4 + 3]);
                }
            }
        }
    }

    __syncthreads();

    if (wid < 2) {
        const int qq = wid;
        const int qj = 2 * qjp + qq;
        float v0 = score[qq * 192 + lane];
        float v1 = score[qq * 192 + 64 + lane];
        float v2 = score[qq * 192 + 128 + lane];
        const int qglob = (t * 48 + qi) * 48 + qj;
        const int vbase = (hd * 9216 + qglob) * 7;
        const int ibase = 129024 + vbase * 3;
        for (int r = 0; r < 7; ++r) {
            float bv = v0; int bi = lane;
            if (v1 > bv) { bv = v1; bi = lane + 64; }
            if (v2 > bv) { bv = v2; bi = lane + 128; }
            #pragma unroll
            for (int m = 1; m <= 32; m <<= 1) {
                float ov = __shfl_xor(bv, m);
                int   oi = __shfl_xor(bi, m);
                if (ov > bv || (ov == bv && oi < bi)) { bv = ov; bi = oi; }
            }
            if (lane == 0) {
                out[vbase + r] = bv;
                int dtSel = bi >> 6;
                int rr    = bi & 63;
                int diSel = (rr >> 3) - 3;
                int djSel = (rr & 7) - 3;
                int ts = t + dtSel - 1;
                ts = ts < 0 ? 0 : (ts > 3 ? 3 : ts);
                int hs = reflect_i(qh + diSel, HH);
                int ws = reflect_i(qj * 4 + djSel, WW);
                float* op = out + ibase + 3 * r;
                op[0] = (float)ts;
                op[1] = (float)hs;
                op[2] = (float)ws;
            }
            if ((bi & 63) == lane) {
                int slot = bi >> 6;
                if (slot == 0)      v0 = -3.4e38f;
                else if (slot == 1) v1 = -3.4e38f;
                else                v2 = -3.4e38f;
            }
        }
    }
}

extern "C" void kernel_launch(void* const* d_in, const int* in_sizes, int n_in,
                              void* d_out, int out_size, void* d_ws, size_t ws_size,
                              hipStream_t stream) {
    const float* vid0 = (const float*)d_in[0];
    const float* vid1 = (const float*)d_in[1];
    float* out = (float*)d_out;
    const size_t need = (size_t)TVID * sizeof(float);   // 37.75 MB
    if (ws_size >= need) {
        float* ws = (float*)d_ws;
        transpose_k<<<dim3(3, 192, 4), 256, 0, stream>>>(vid1, ws);
        nls_fast<<<dim3(9216), 256, 0, stream>>>(vid0, ws, out);
    } else {
        nls_kernel<<<dim3(9216), 256, 0, stream>>>(vid0, vid1, out);
    }
}

// Round 9
// 331.387 us; speedup vs baseline: 1.0598x; 1.0598x over previous
//
#include <hip/hip_runtime.h>

// NLSearch: B=1, T=4, C=64 (2 heads x 32ch), H=W=192, stride0=4 -> 48x48 queries,
// patch 7x7, offsets dt{-1,0,1} x di,dj{-3..4} (L=192), top-K=7.
// Out: vals f32 [2][9216][7] (129024) then inds [2][9216][7][3] (387072).
//
// R9 structure: transpose BOTH vids -> [t][h][w][c] in d_ws (coalesced lane=c
// reads). Main kernel is staging-free (A direct from T0, B direct from T1),
// barrier-free dt loop (dup-dt slots written from the same acc registers ->
// bitwise-equal scores, jax top_k lower-index tie-break exact), and an
// explicit 3-row rotating prefetch pipeline so each row's 10 global loads have
// ~2 rows of FMA (~450 cyc) in flight before s_waitcnt (R8's VGPR=88 proved
// the compiler buffers only 1 row on its own -> full L2/L3 latency per row).
//
// Hard-won lessons kept:
//  - NO min-waves arg in __launch_bounds__: (256,3)->84 and (256,4)->64 VGPR
//    caps spilled a[]/acc[] to scratch (R3: 3.1 GB scratch HBM traffic).
//  - A-patch loads must be coalesced-from-transposed (R8's LDS stage from
//    original layout cost +27us of per-block serial latency).
//  - Fatter blocks beat thin ones (R6). LDS odd strides / none at all.
//  - Fallback to the proven R5 LDS kernel if ws_size < 75.5 MB.

#define HH 192
#define WW 192
#define HW (HH * WW)
#define TSLICE (192 * 192 * 64)   // one t-slice of a transposed video (floats)
#define ROWST  (192 * 64)         // h-row stride in transposed layout (floats)
#define TVID   (4 * TSLICE)

__device__ __forceinline__ int reflect_i(int idx, int n) {
    idx = idx < 0 ? -idx : idx;
    idx = idx >= n ? 2 * (n - 1) - idx : idx;
    return idx;
}

template <int CTRL>
__device__ __forceinline__ float dpp_add(float x) {
    int y = __builtin_amdgcn_update_dpp(0, __float_as_int(x), CTRL, 0xf, 0xf, true);
    return x + __int_as_float(y);
}

// lane31 <- sum(lanes 0..31), lane63 <- sum(lanes 32..63); VALU pipe, no LDS.
__device__ __forceinline__ float reduce32(float v) {
    v = dpp_add<0x111>(v);  // row_shr:1
    v = dpp_add<0x112>(v);  // row_shr:2
    v = dpp_add<0x114>(v);  // row_shr:4
    v = dpp_add<0x118>(v);  // row_shr:8
    v = dpp_add<0x142>(v);  // row_bcast15
    return v;
}

// ---------------- transpose [t][c][h][w] -> [t][h][w][c], both vids ----------
__global__ __launch_bounds__(256) void transpose_k(
    const float* __restrict__ v0, const float* __restrict__ v1,
    float* __restrict__ ws)
{
    __shared__ float tile[64 * 65];
    const int wt  = blockIdx.x;      // 0..2  (w tile of 64)
    const int h   = blockIdx.y;      // 0..191
    const int z   = blockIdx.z;      // vid*4 + t
    const int vid = z >> 2;
    const int t   = z & 3;
    const int w0  = wt * 64;
    const int tid = threadIdx.x;
    const int a   = tid & 63;
    const int g   = tid >> 6;
    const float* src = (vid ? v1 : v0) + (size_t)t * 64 * HW + h * WW + w0;
    float* dst = ws + (size_t)vid * TVID + ((size_t)(t * 192 + h) * 192 + w0) * 64;
    #pragma unroll
    for (int cc = g; cc < 64; cc += 4)
        tile[cc * 65 + a] = src[(size_t)cc * HW + a];
    __syncthreads();
    #pragma unroll
    for (int ww = g; ww < 64; ww += 4)
        dst[ww * 64 + a] = tile[a * 65 + ww];
}

// ---------------- main kernel: barrier-free, 3-row prefetch pipeline ---------
__global__ __launch_bounds__(256) void nls_fast(
    const float* __restrict__ T0,
    const float* __restrict__ T1,
    float* __restrict__ out)
{
    __shared__ float score[2 * 192];

    // XCD swizzle: xcd = blk&7 -> qi band of 6; inner (hd, t, qi_l, qjp fastest)
    const int b    = blockIdx.x;
    const int xcd  = b & 7;
    const int loc  = b >> 3;
    const int qjp  = loc % 24;
    const int r1   = loc / 24;
    const int qi_l = r1 % 6;
    const int r2   = r1 / 6;
    const int t    = r2 & 3;
    const int hd   = r2 >> 2;
    const int qi   = xcd * 6 + qi_l;

    const int qh  = qi * 4;
    const int qw0 = qjp * 8;

    const int tid  = threadIdx.x;
    const int lane = tid & 63;
    const int wid  = tid >> 6;

    const int c     = lane & 31;
    const int hhalf = lane >> 5;   // dj half: 0 -> dj 0..3, 1 -> dj 4..7
    const int q     = wid >> 1;    // query in pair
    const int d     = wid & 1;     // di half: rows 4d..4d+3
    const int cg    = hd * 32 + c;
    const int qwq   = qw0 + 4 * q;

    // ---- A patch -> regs (coalesced: 32 contiguous c per half-wave) ----
    float a[7][7];
    {
        #pragma unroll
        for (int y = 0; y < 7; ++y) {
            const int hv = reflect_i(qh - 3 + y, HH);
            const float* rp = T0 + (size_t)(t * 192 + hv) * ROWST + cg;
            #pragma unroll
            for (int x = 0; x < 7; ++x) {
                const int wv = reflect_i(qwq - 3 + x, WW);
                a[y][x] = rp[wv * 64];
            }
        }
    }

    const bool interior = (qi >= 2) && (qi <= 46) && (qjp >= 1) && (qjp <= 22);

#define FMA_BLOCK(RWBUF)                                                 \
    {                                                                    \
        const int dlo = r > 6 ? r - 6 : 0;                               \
        const int dhi = r < 3 ? r : 3;                                   \
        _Pragma("unroll")                                                \
        for (int dip = 0; dip < 4; ++dip) {                              \
            if (dip >= dlo && dip <= dhi) {                              \
                const int y = r - dip;                                   \
                _Pragma("unroll")                                        \
                for (int djp = 0; djp < 4; ++djp) {                      \
                    _Pragma("unroll")                                    \
                    for (int x = 0; x < 7; ++x) {                        \
                        acc[dip * 4 + djp] =                             \
                            fmaf(a[y][x], (RWBUF)[djp + x], acc[dip * 4 + djp]); \
                    }                                                    \
                }                                                        \
            }                                                            \
        }                                                                \
    }

    // ---- 3-dt loop, NO barriers; dup dt re-uses the same registers ----
    float acc[16];
    int tprev = -1;
    #pragma unroll
    for (int dtI = 0; dtI < 3; ++dtI) {
        int tp = t + dtI - 1;
        tp = tp < 0 ? 0 : (tp > 3 ? 3 : tp);

        if (tp != tprev) {
            tprev = tp;
            #pragma unroll
            for (int k = 0; k < 16; ++k) acc[k] = 0.f;

            float rwb[3][10];   // rotating 3-row prefetch buffers

            if (interior) {
                const float* P = T1 + (size_t)(tp * 192 + qh - 6 + 4 * d) * ROWST
                               + (qwq - 6 + 4 * hhalf) * 64 + cg;
                #pragma unroll
                for (int v = 0; v < 10; ++v) rwb[0][v] = P[v * 64];
                #pragma unroll
                for (int v = 0; v < 10; ++v) rwb[1][v] = P[ROWST + v * 64];
                #pragma unroll
                for (int r = 0; r < 10; ++r) {
                    if (r + 2 < 10) {
                        const float* pr = P + (size_t)(r + 2) * ROWST;
                        #pragma unroll
                        for (int v = 0; v < 10; ++v)
                            rwb[(r + 2) % 3][v] = pr[v * 64];
                    }
                    FMA_BLOCK(rwb[r % 3])
                }
            } else {
                int wo[10];
                #pragma unroll
                for (int v = 0; v < 10; ++v)
                    wo[v] = reflect_i(qwq - 6 + 4 * hhalf + v, WW) * 64 + cg;
                const float* Pt = T1 + (size_t)tp * TSLICE;
                {
                    const float* pr0 = Pt + (size_t)reflect_i(qh - 6 + 4 * d, HH) * ROWST;
                    const float* pr1 = Pt + (size_t)reflect_i(qh - 5 + 4 * d, HH) * ROWST;
                    #pragma unroll
                    for (int v = 0; v < 10; ++v) rwb[0][v] = pr0[wo[v]];
                    #pragma unroll
                    for (int v = 0; v < 10; ++v) rwb[1][v] = pr1[wo[v]];
                }
                #pragma unroll
                for (int r = 0; r < 10; ++r) {
                    if (r + 2 < 10) {
                        const int hv = reflect_i(qh - 6 + 4 * d + r + 2, HH);
                        const float* pr = Pt + (size_t)hv * ROWST;
                        #pragma unroll
                        for (int v = 0; v < 10; ++v)
                            rwb[(r + 2) % 3][v] = pr[wo[v]];
                    }
                    FMA_BLOCK(rwb[r % 3])
                }
            }

            // channel reduction on VALU; lane31 -> hhalf0, lane63 -> hhalf1
            #pragma unroll
            for (int k = 0; k < 16; ++k) acc[k] = reduce32(acc[k]);
        }

        // write this dt's slot (dup dt writes identical bits -> exact ties)
        if ((lane & 31) == 31) {
            float* sp = &score[q * 192 + dtI * 64 + 4 * hhalf];
            #pragma unroll
            for (int dip = 0; dip < 4; ++dip)
                #pragma unroll
                for (int djp = 0; djp < 4; ++djp)
                    sp[(4 * d + dip) * 8 + djp] = acc[dip * 4 + djp];
        }
    }
#undef FMA_BLOCK

    __syncthreads();

    // ---- top-K=7 over 192 per query; waves 0,1 ----
    if (wid < 2) {
        const int qq = wid;
        const int qj = 2 * qjp + qq;
        float v0 = score[qq * 192 + lane];
        float v1 = score[qq * 192 + 64 + lane];
        float v2 = score[qq * 192 + 128 + lane];
        const int qglob = (t * 48 + qi) * 48 + qj;
        const int vbase = (hd * 9216 + qglob) * 7;
        const int ibase = 129024 + vbase * 3;
        for (int r = 0; r < 7; ++r) {
            float bv = v0; int bi = lane;
            if (v1 > bv) { bv = v1; bi = lane + 64; }
            if (v2 > bv) { bv = v2; bi = lane + 128; }
            #pragma unroll
            for (int m = 1; m <= 32; m <<= 1) {
                float ov = __shfl_xor(bv, m);
                int   oi = __shfl_xor(bi, m);
                if (ov > bv || (ov == bv && oi < bi)) { bv = ov; bi = oi; }
            }
            if (lane == 0) {
                out[vbase + r] = bv;
                int dtSel = bi >> 6;
                int rr    = bi & 63;
                int diSel = (rr >> 3) - 3;
                int djSel = (rr & 7) - 3;
                int ts = t + dtSel - 1;
                ts = ts < 0 ? 0 : (ts > 3 ? 3 : ts);
                int hs = reflect_i(qh + diSel, HH);
                int ws = reflect_i(qj * 4 + djSel, WW);
                float* op = out + ibase + 3 * r;
                op[0] = (float)ts;
                op[1] = (float)hs;
                op[2] = (float)ws;
            }
            if ((bi & 63) == lane) {
                int slot = bi >> 6;
                if (slot == 0)      v0 = -3.4e38f;
                else if (slot == 1) v1 = -3.4e38f;
                else                v2 = -3.4e38f;
            }
        }
    }
}

// ---------------- fallback (proven R5 kernel, 331 us) if ws too small --------
#define BS_CSTR 282
#define BS_SZ   (32 * BS_CSTR)
#define AF_CSTR 86

__global__ __launch_bounds__(256) void nls_kernel(
    const float* __restrict__ vid0,
    const float* __restrict__ vid1,
    float* __restrict__ out)
{
    __shared__ float smem[BS_SZ + 2 * 192];
    float* Bs = smem;
    float* Asf = smem;
    float* score = smem + BS_SZ;

    const int b    = blockIdx.x;
    const int xcd  = b & 7;
    const int loc  = b >> 3;
    const int qjp  = loc % 24;
    const int r1   = loc / 24;
    const int qi_l = r1 % 6;
    const int r2   = r1 / 6;
    const int t    = r2 & 3;
    const int hd   = r2 >> 2;
    const int qi   = xcd * 6 + qi_l;

    const int qh  = qi * 4;
    const int qw0 = qjp * 8;

    const int tid  = threadIdx.x;
    const int lane = tid & 63;
    const int wid  = tid >> 6;

    const bool intA = (qi >= 1) && (qjp >= 1) && (qjp <= 22);
    const bool intB = (qi >= 2) && (qi <= 46) && (qjp >= 1) && (qjp <= 22);

    if (intA) {
        const int sc = tid & 31;
        const int gg = tid >> 5;
        const float* src = vid0 + (size_t)(t * 64 + hd * 32 + sc) * HW
                         + (qh - 3) * WW + (qw0 - 3);
        float* dstc = Asf + sc * AF_CSTR;
        for (int it = gg; it < 21; it += 8) {
            int u = it / 3, grp = it - u * 3;
            float4 val = *(const float4*)(src + u * WW + 4 * grp);
            float* dp = dstc + u * 12 + 4 * grp;
            *(float2*)(dp)     = make_float2(val.x, val.y);
            *(float2*)(dp + 2) = make_float2(val.z, val.w);
        }
    } else {
        const int sc = tid >> 3;
        const int vl = tid & 7;
        const float* src = vid0 + (size_t)(t * 64 + hd * 32 + sc) * HW;
        const int wa0 = reflect_i(qw0 - 3 + vl, WW);
        const int wa1 = (vl < 4) ? reflect_i(qw0 + 5 + vl, WW) : 0;
        float* dst = Asf + sc * AF_CSTR + vl;
        #pragma unroll
        for (int u = 0; u < 7; ++u) {
            int hh = reflect_i(qh - 3 + u, HH);
            const float* rp = src + hh * WW;
            dst[u * 12] = rp[wa0];
            if (vl < 4) dst[u * 12 + 8] = rp[wa1];
        }
    }
    __syncthreads();

    const int c     = lane & 31;
    const int hhalf = lane >> 5;
    const int q     = wid >> 1;
    const int d     = wid & 1;

    float a[7][8];
    {
        const float* Ab = Asf + c * AF_CSTR + 4 * q;
        #pragma unroll
        for (int y = 0; y < 7; ++y) {
            #pragma unroll
            for (int j = 0; j < 4; ++j)
                *(float2*)&a[y][2 * j] = *(const float2*)(Ab + y * 12 + 2 * j);
        }
    }

    const float* Bc = Bs + c * BS_CSTR + (4 * d) * 20 + 4 * q + 4 * hhalf;

    int tprev = -1;
    for (int dtI = 0; dtI < 3; ++dtI) {
        int tp = t + dtI - 1;
        tp = tp < 0 ? 0 : (tp > 3 ? 3 : tp);
        __syncthreads();
        if (tp == tprev) {
            if (tid < 128) {
                int qq = tid >> 6, o = tid & 63;
                score[qq * 192 + dtI * 64 + o] = score[qq * 192 + (dtI - 1) * 64 + o];
            }
            continue;
        }
        tprev = tp;

        if (intB) {
            const int sc = tid & 31;
            const int gg = tid >> 5;
            const float* src = vid1 + (size_t)(tp * 64 + hd * 32 + sc) * HW
                             + (qh - 6) * WW + (qw0 - 6);
            float* dstc = Bs + sc * BS_CSTR;
            for (int it = gg; it < 70; it += 8) {
                int u = it / 5, grp = it - u * 5;
                float4 val = *(const float4*)(src + u * WW + 4 * grp);
                float* dp = dstc + u * 20 + 4 * grp;
                *(float2*)(dp)     = make_float2(val.x, val.y);
                *(float2*)(dp + 2) = make_float2(val.z, val.w);
            }
        } else {
            const int sc = tid >> 3;
            const int vl = tid & 7;
            const float* src = vid1 + (size_t)(tp * 64 + hd * 32 + sc) * HW;
            const int w0 = reflect_i(qw0 - 6 + vl, WW);
            const int w1 = reflect_i(qw0 + 2 + vl, WW);
            const int w2 = (vl < 4) ? reflect_i(qw0 + 10 + vl, WW) : 0;
            float* dst = Bs + sc * BS_CSTR + vl;
            #pragma unroll
            for (int u = 0; u < 14; ++u) {
                int hh2 = reflect_i(qh - 6 + u, HH);
                const float* rp = src + hh2 * WW;
                dst[u * 20]     = rp[w0];
                dst[u * 20 + 8] = rp[w1];
                if (vl < 4) dst[u * 20 + 16] = rp[w2];
            }
        }
        __syncthreads();

        {
            float acc[16];
            #pragma unroll
            for (int k = 0; k < 16; ++k) acc[k] = 0.f;
            #pragma unroll
            for (int r = 0; r < 10; ++r) {
                float rw[12];
                const float* Br = Bc + r * 20;
                #pragma unroll
                for (int j = 0; j < 6; ++j)
                    *(float2*)&rw[2 * j] = *(const float2*)(Br + 2 * j);
                const int dlo = r > 6 ? r - 6 : 0;
                const int dhi = r < 3 ? r : 3;
                #pragma unroll
                for (int dip = 0; dip < 4; ++dip) {
                    if (dip >= dlo && dip <= dhi) {
                        const int y = r - dip;
                        #pragma unroll
                        for (int djp = 0; djp < 4; ++djp)
                            #pragma unroll
                            for (int x = 0; x < 7; ++x)
                                acc[dip * 4 + djp] =
                                    fmaf(a[y][x], rw[djp + x], acc[dip * 4 + djp]);
                    }
                }
            }
            #pragma unroll
            for (int k = 0; k < 16; ++k) acc[k] = reduce32(acc[k]);
            if ((lane & 31) == 31) {
                float* sp = &score[q * 192 + dtI * 64 + 4 * hhalf];
                #pragma unroll
                for (int dip = 0; dip < 4; ++dip) {
                    float* dp = sp + (4 * d + dip) * 8;
                    *(float2*)(dp)     = make_float2(acc[dip * 4 + 0], acc[dip * 4 + 1]);
                    *(float2*)(dp + 2) = make_float2(acc[dip * 4 + 2], acc[dip * 4 + 3]);
                }
            }
        }
    }

    __syncthreads();

    if (wid < 2) {
        const int qq = wid;
        const int qj = 2 * qjp + qq;
        float v0 = score[qq * 192 + lane];
        float v1 = score[qq * 192 + 64 + lane];
        float v2 = score[qq * 192 + 128 + lane];
        const int qglob = (t * 48 + qi) * 48 + qj;
        const int vbase = (hd * 9216 + qglob) * 7;
        const int ibase = 129024 + vbase * 3;
        for (int r = 0; r < 7; ++r) {
            float bv = v0; int bi = lane;
            if (v1 > bv) { bv = v1; bi = lane + 64; }
            if (v2 > bv) { bv = v2; bi = lane + 128; }
            #pragma unroll
            for (int m = 1; m <= 32; m <<= 1) {
                float ov = __shfl_xor(bv, m);
                int   oi = __shfl_xor(bi, m);
                if (ov > bv || (ov == bv && oi < bi)) { bv = ov; bi = oi; }
            }
            if (lane == 0) {
                out[vbase + r] = bv;
                int dtSel = bi >> 6;
                int rr    = bi & 63;
                int diSel = (rr >> 3) - 3;
                int djSel = (rr & 7) - 3;
                int ts = t + dtSel - 1;
                ts = ts < 0 ? 0 : (ts > 3 ? 3 : ts);
                int hs = reflect_i(qh + diSel, HH);
                int ws = reflect_i(qj * 4 + djSel, WW);
                float* op = out + ibase + 3 * r;
                op[0] = (float)ts;
                op[1] = (float)hs;
                op[2] = (float)ws;
            }
            if ((bi & 63) == lane) {
                int slot = bi >> 6;
                if (slot == 0)      v0 = -3.4e38f;
                else if (slot == 1) v1 = -3.4e38f;
                else                v2 = -3.4e38f;
            }
        }
    }
}

extern "C" void kernel_launch(void* const* d_in, const int* in_sizes, int n_in,
                              void* d_out, int out_size, void* d_ws, size_t ws_size,
                              hipStream_t stream) {
    const float* vid0 = (const float*)d_in[0];
    const float* vid1 = (const float*)d_in[1];
    float* out = (float*)d_out;
    const size_t need = 2ull * (size_t)TVID * sizeof(float);   // 75.5 MB
    if (ws_size >= need) {
        float* ws = (float*)d_ws;
        transpose_k<<<dim3(3, 192, 8), 256, 0, stream>>>(vid0, vid1, ws);
        nls_fast<<<dim3(9216), 256, 0, stream>>>(ws, ws + TVID, out);
    } else {
        nls_kernel<<<dim3(9216), 256, 0, stream>>>(vid0, vid1, out);
    }
}